// Round 7
// baseline (580.734 us; speedup 1.0000x reference)
//
#include <hip/hip_runtime.h>
#include <math.h>
#include <stdint.h>

#define BB 4
#define NN 4096
#define DD 1024
#define TT (BB * NN)          // 16384 tokens
#define NC 64                 // scan chunks
#define CL (NN / NC)          // 64 steps per chunk

typedef __attribute__((ext_vector_type(8))) short bf16x8;
typedef __attribute__((ext_vector_type(4))) float f32x4;

// bf16 round-to-nearest-even (returns top-16 bit pattern)
__device__ inline unsigned short bf_rne(float v) {
  union { float f; uint32_t u; } x; x.f = v;
  uint32_t r = x.u + 0x7fffu + ((x.u >> 16) & 1u);
  return (unsigned short)(r >> 16);
}
__device__ inline float bf_to_f(unsigned short h) {
  union { float f; uint32_t u; } x; x.u = ((uint32_t)h) << 16;
  return x.f;
}

// async global->LDS, 16 bytes per lane, deposits at (wave-uniform base + lane*16)
__device__ inline void async16(const void* g, void* l) {
  __builtin_amdgcn_global_load_lds(
      (const __attribute__((address_space(1))) uint32_t*)g,
      (__attribute__((address_space(3))) uint32_t*)l, 16, 0, 0);
}

// ---------------------------------------------------------------------------
// conv_x: x (b,n,d) fp32 -> Abf (t = n*4+b, 1024) bf16
// ---------------------------------------------------------------------------
__global__ __launch_bounds__(256) void conv_x_kernel(
    const float* __restrict__ x, unsigned short* __restrict__ Abf) {
  int idx = blockIdx.x * 256 + threadIdx.x;     // over BB*NN*DD
  int k = idx & 1023;
  int n = (idx >> 10) & 4095;
  int b = idx >> 22;
  Abf[(size_t)(n * 4 + b) * 1024 + k] = bf_rne(x[idx]);
}

// ---------------------------------------------------------------------------
// conv_w1: rows [in_w(2048); nu_w(1024)] (e,1024) fp32 -> W1 bf16
// ---------------------------------------------------------------------------
__global__ __launch_bounds__(256) void conv_w1_kernel(
    const float* __restrict__ in_w, const float* __restrict__ nu_w,
    unsigned short* __restrict__ W1) {
  int idx = blockIdx.x * 256 + threadIdx.x;     // over 3072*1024
  float v = (idx < 2048 * 1024) ? in_w[idx] : nu_w[idx - 2048 * 1024];
  W1[idx] = bf_rne(v);
}

// ---------------------------------------------------------------------------
// conv_w2: out_w (j, 2048) fp32 -> W2 (j, 2048) bf16, (r,i)-interleaved:
// W2[j][2d] = out_w[j][d], W2[j][2d+1] = out_w[j][1024+d]
// ---------------------------------------------------------------------------
__global__ __launch_bounds__(256) void conv_w2_kernel(
    const float* __restrict__ out_w, unsigned short* __restrict__ W2) {
  int idx = blockIdx.x * 256 + threadIdx.x;     // over 1024*1024
  int j = idx >> 10, d = idx & 1023;
  W2[(size_t)j * 2048 + 2 * d]     = bf_rne(out_w[(size_t)j * 2048 + d]);
  W2[(size_t)j * 2048 + 2 * d + 1] = bf_rne(out_w[(size_t)j * 2048 + 1024 + d]);
}

// ---------------------------------------------------------------------------
// GEMM1 (MFMA): z = Abf[t,:] . W1[e,:], K=1024 bf16.
// 256x256 tile, BK=64, 8 waves (2Mx4N), 512 thr, __launch_bounds__(512,2).
// Round-11 change (r3/r4/r6 all ~22% MfmaUtil -> schedule-invariant pole is
// LDS amplification: 64KB staged + 192KB re-read per tile >= MFMA floor):
// B (W1) BYPASSES LDS -- each wave loads its own B fragments global->VGPR
// as dwordx4 (16 full cache lines per instr; W1 panel L2-hot under the T1
// band order). LDS now A-only: traffic 256->160 KB/tile (< 2048cy MFMA
// floor); staging 4 loads/wave -> vmcnt(4); LDS 64 KB; B waits are
// compiler-counted vmcnt, decoupled from barriers. B loads issued BEFORE
// the tile barrier (no LDS dep) so L2 latency hides under barrier+af reads.
// T1 XCD swizzle kept (FETCH at the 74MB partitioned floor, verified r6).
// Epilogue:
//   e < 2048 : U16[t,e]  = bf16( gamma[e>>1]*(z + in_b[e]) )   (u interleaved)
//   e >= 2048: NU[t,e']  = fp16( sigmoid(z + nu_b[e']) )
// ---------------------------------------------------------------------------
__global__ __launch_bounds__(512, 2) void gemm1_mfma(
    const unsigned short* __restrict__ A,
    const unsigned short* __restrict__ W1,
    const float* __restrict__ in_b, const float* __restrict__ nu_b,
    const float* __restrict__ gamma_log,
    unsigned short* __restrict__ U16, _Float16* __restrict__ NU) {
  __shared__ unsigned short As[2][16384];   // 2 x 32 KB, A only
  const int tid = threadIdx.x;
  const int w = tid >> 6, l = tid & 63;
  const int q = l >> 4, ml = l & 15;
  // XCD-chunked swizzle (T1)
  const int orig = blockIdx.x + gridDim.x * blockIdx.y;   // 0..767
  const int xcd = orig & 7;
  const int jj_ = orig >> 3;            // 0..95
  const int ntile = jj_ >> 3;           // 0..11
  const int mloc = jj_ & 7;             // 0..7
  const int m0 = (xcd * 8 + mloc) * 256;
  const int n0 = ntile * 256;
  const int wm = w & 1, wn = w >> 1;    // wm: row half, wn: col quarter

  f32x4 acc[8][4] = {};

  // A staging: wave w owns k-slice kq=w, 4 row-groups -> 4 async16/wave
  auto stageA = [&](int p, int k0) {
#pragma unroll
    for (int rg = 0; rg < 4; ++rg)
      async16(A + (size_t)(m0 + rg * 64 + l) * 1024 + k0 + w * 8,
              &As[p][(w * 256 + rg * 64) * 8]);
  };

  // B fragment base: lane reads W1[col][k0 + (ks*4+q)*8 .. +8]
  const unsigned short* Bp = W1 + (size_t)(n0 + wn * 64 + ml) * 1024 + q * 8;

  stageA(0, 0);               // 4 loads in flight
  int cur = 0;
  for (int k0 = 0; k0 < 1024; k0 += 64) {
    const bool last = (k0 + 64 >= 1024);
    // B loads for THIS tile: no LDS dependence -> issue before the barrier
    bf16x8 bfr[2][4];
#pragma unroll
    for (int ks = 0; ks < 2; ++ks)
#pragma unroll
      for (int j = 0; j < 4; ++j)
        bfr[ks][j] = *(const bf16x8*)(Bp + (size_t)j * 16 * 1024 + k0 + ks * 32);
    if (!last) {
      stageA(cur ^ 1, k0 + 64);                         // +4 outstanding
      asm volatile("s_waitcnt vmcnt(4)" ::: "memory");  // all but newest 4:
      // prev-tile A staged AND this tile's B retired (FIFO)
    } else {
      asm volatile("s_waitcnt vmcnt(0)" ::: "memory");
    }
    __builtin_amdgcn_s_barrier();        // As[cur] fully staged (all waves)
    __builtin_amdgcn_sched_barrier(0);   // keep af reads below the barrier
#pragma unroll
    for (int ks = 0; ks < 2; ++ks) {
      bf16x8 af[8];
#pragma unroll
      for (int i = 0; i < 8; ++i)
        af[i] = *(const bf16x8*)&As[cur][(((ks * 4 + q) * 256) + wm * 128 + i * 16 + ml) * 8];
#pragma unroll
      for (int i = 0; i < 8; ++i)
#pragma unroll
        for (int j = 0; j < 4; ++j)
          acc[i][j] = __builtin_amdgcn_mfma_f32_16x16x32_bf16(af[i], bfr[ks][j], acc[i][j], 0, 0, 0);
    }
    __builtin_amdgcn_sched_barrier(0);   // af reads consumed before barrier
    __builtin_amdgcn_s_barrier();        // all waves done reading As[cur]
    cur ^= 1;
  }

  if (n0 < 2048) {   // u columns (block-uniform)
#pragma unroll
    for (int j = 0; j < 4; ++j) {
      int col = n0 + wn * 64 + j * 16 + ml;
      float bias = in_b[col];
      float gam = expf(gamma_log[col >> 1]);
#pragma unroll
      for (int i = 0; i < 8; ++i) {
        int trow = m0 + wm * 128 + i * 16 + q * 4;
#pragma unroll
        for (int v = 0; v < 4; ++v)
          U16[(size_t)(trow + v) * 2048 + col] = bf_rne(gam * (acc[i][j][v] + bias));
      }
    }
  } else {           // nu columns
#pragma unroll
    for (int j = 0; j < 4; ++j) {
      int col = n0 + wn * 64 + j * 16 + ml;
      int c2 = col - 2048;
      float bias = nu_b[c2];
#pragma unroll
      for (int i = 0; i < 8; ++i) {
        int trow = m0 + wm * 128 + i * 16 + q * 4;
#pragma unroll
        for (int v = 0; v < 4; ++v) {
          float z = acc[i][j][v] + bias;
          NU[(size_t)(trow + v) * 1024 + c2] = (_Float16)(1.f / (1.f + expf(-z)));
        }
      }
    }
  }
}

// ---------------------------------------------------------------------------
// Scan phase 1: per (chunk c, batch b, channel dch) local scan from h=0.
// Emits (A_r, A_i, hend_r, hend_i), A = prod of lambda over the chunk.
// ---------------------------------------------------------------------------
__global__ __launch_bounds__(256) void scan_p1_kernel(
    const unsigned short* __restrict__ U16, const _Float16* __restrict__ NU,
    const float* __restrict__ theta_log,
    float* __restrict__ chunkA) {
  int s = blockIdx.x * 256 + threadIdx.x;   // ((c*BB)+b)*DD + dch
  int dch = s & (DD - 1);
  int b = (s >> 10) & (BB - 1);
  int c = s >> 12;
  float theta = expf(theta_log[dch]);
  float ct = cosf(theta), st = sinf(theta);
  float hr = 0.f, hi = 0.f, Ar = 1.f, Ai = 0.f;
  for (int i = 0; i < CL; ++i) {
    int t = (c * CL + i) * 4 + b;
    ushort2 up = *(const ushort2*)(U16 + (size_t)t * 2048 + 2 * dch);
    float ur = bf_to_f(up.x), ui = bf_to_f(up.y);
    float nu = (float)NU[(size_t)t * 1024 + dch];
    float lr = nu * ct, li = nu * st;
    float hr2 = lr * hr - li * hi + ur;
    float hi2 = lr * hi + li * hr + ui;
    hr = hr2; hi = hi2;
    float Ar2 = lr * Ar - li * Ai;
    float Ai2 = lr * Ai + li * Ar;
    Ar = Ar2; Ai = Ai2;
  }
  float4 o = {Ar, Ai, hr, hi};
  *(float4*)(chunkA + (size_t)s * 4) = o;
}

// ---------------------------------------------------------------------------
// Scan phase 2: compose NC chunk summaries per channel; overwrite each
// entry's (z,w) slots in-place with that chunk's carry-in state.
// ---------------------------------------------------------------------------
__global__ __launch_bounds__(256) void scan_p2_kernel(
    float* __restrict__ chunkA) {
  int qx = blockIdx.x * 256 + threadIdx.x;   // b*DD + dch
  int dch = qx & (DD - 1);
  int b = qx >> 10;
  float cr = 0.f, ci = 0.f;
  for (int c = 0; c < NC; ++c) {
    size_t idx = ((size_t)(c * BB + b) * DD + dch) * 4;
    float4 v = *(const float4*)(chunkA + idx);
    float2 wv = {cr, ci};
    *(float2*)(chunkA + idx + 2) = wv;      // carry-in for chunk c
    float nr = v.x * cr - v.y * ci + v.z;
    float ni = v.x * ci + v.y * cr + v.w;
    cr = nr; ci = ni;
  }
}

// ---------------------------------------------------------------------------
// Scan phase 3: block per (c,b); re-run chunk from carry-in; overwrite u
// bf16 pairs IN-PLACE with feature bf16 pairs: U16[t][2d]=bf16(h_r[d]),
// U16[t][2d+1]=bf16(h_i[d]). Each thread reads and writes the SAME 16 bytes
// (channels 4*tid..4*tid+3) -> no __syncthreads needed, pure streaming.
// ---------------------------------------------------------------------------
__global__ __launch_bounds__(256) void scan_p3_kernel(
    unsigned short* __restrict__ U16, const _Float16* __restrict__ NU,
    const float* __restrict__ theta_log, const float* __restrict__ chunkA) {
  const int c = blockIdx.x >> 2, b = blockIdx.x & 3;
  const int tid = threadIdx.x;
  float ct[4], st[4], hr[4], hi_[4];
#pragma unroll
  for (int dj = 0; dj < 4; ++dj) {
    int d = tid * 4 + dj;
    float th = expf(theta_log[d]);
    ct[dj] = cosf(th); st[dj] = sinf(th);
    const float* cp = chunkA + ((size_t)((c * 4 + b) * 1024) + d) * 4 + 2;
    hr[dj] = cp[0]; hi_[dj] = cp[1];
  }
  for (int i = 0; i < CL; ++i) {
    int t = (c * CL + i) * 4 + b;
    unsigned short* up = U16 + (size_t)t * 2048 + 8 * tid;
    bf16x8 uv = *(const bf16x8*)up;
    const _Float16* nup = NU + (size_t)t * 1024 + 4 * tid;
    bf16x8 fo;
#pragma unroll
    for (int dj = 0; dj < 4; ++dj) {
      float nu = (float)nup[dj];
      float lr = nu * ct[dj], li = nu * st[dj];
      float nhr = lr * hr[dj] - li * hi_[dj] + bf_to_f((unsigned short)uv[2 * dj]);
      float nhi = lr * hi_[dj] + li * hr[dj] + bf_to_f((unsigned short)uv[2 * dj + 1]);
      hr[dj] = nhr; hi_[dj] = nhi;
      fo[2 * dj] = (short)bf_rne(nhr);
      fo[2 * dj + 1] = (short)bf_rne(nhi);
    }
    *(bf16x8*)up = fo;
  }
}

// ---------------------------------------------------------------------------
// GEMM2 (MFMA): out[t][j] = F[t,:] . W2[j,:] + out_b[j], K=2048 bf16, BK=64.
// F = U16 after scan_p3 (contiguous rows, stride 2048 shorts).
// Same A-via-LDS / B-direct-to-VGPR structure as gemm1 (W2 = 4MB, L2-hot
// per XCD). XCD swizzle: n-fastest within each XCD band.
// ---------------------------------------------------------------------------
__global__ __launch_bounds__(512, 2) void gemm2_mfma(
    const unsigned short* __restrict__ F,
    const unsigned short* __restrict__ W2,
    const float* __restrict__ out_b,
    float* __restrict__ out) {
  __shared__ unsigned short As[2][16384];
  const int tid = threadIdx.x;
  const int w = tid >> 6, l = tid & 63;
  const int q = l >> 4, ml = l & 15;
  const int orig = blockIdx.x + gridDim.x * blockIdx.y;   // 0..255
  const int xcd = orig & 7;
  const int jj_ = orig >> 3;            // 0..31
  const int mloc = jj_ >> 2;            // 0..7
  const int ntile = jj_ & 3;            // 0..3
  const int m0 = (xcd * 8 + mloc) * 256;
  const int n0 = ntile * 256;
  const int wm = w & 1, wn = w >> 1;

  f32x4 acc[8][4] = {};

  auto stageA = [&](int p, int k0) {
#pragma unroll
    for (int rg = 0; rg < 4; ++rg)
      async16(F + (size_t)(m0 + rg * 64 + l) * 2048 + k0 + w * 8,
              &As[p][(w * 256 + rg * 64) * 8]);
  };

  const unsigned short* Bp = W2 + (size_t)(n0 + wn * 64 + ml) * 2048 + q * 8;

  stageA(0, 0);
  int cur = 0;
  for (int k0 = 0; k0 < 2048; k0 += 64) {
    const bool last = (k0 + 64 >= 2048);
    bf16x8 bfr[2][4];
#pragma unroll
    for (int ks = 0; ks < 2; ++ks)
#pragma unroll
      for (int j = 0; j < 4; ++j)
        bfr[ks][j] = *(const bf16x8*)(Bp + (size_t)j * 16 * 2048 + k0 + ks * 32);
    if (!last) {
      stageA(cur ^ 1, k0 + 64);
      asm volatile("s_waitcnt vmcnt(4)" ::: "memory");
    } else {
      asm volatile("s_waitcnt vmcnt(0)" ::: "memory");
    }
    __builtin_amdgcn_s_barrier();
    __builtin_amdgcn_sched_barrier(0);
#pragma unroll
    for (int ks = 0; ks < 2; ++ks) {
      bf16x8 af[8];
#pragma unroll
      for (int i = 0; i < 8; ++i)
        af[i] = *(const bf16x8*)&As[cur][(((ks * 4 + q) * 256) + wm * 128 + i * 16 + ml) * 8];
#pragma unroll
      for (int i = 0; i < 8; ++i)
#pragma unroll
        for (int j = 0; j < 4; ++j)
          acc[i][j] = __builtin_amdgcn_mfma_f32_16x16x32_bf16(af[i], bfr[ks][j], acc[i][j], 0, 0, 0);
    }
    __builtin_amdgcn_sched_barrier(0);
    __builtin_amdgcn_s_barrier();
    cur ^= 1;
  }

#pragma unroll
  for (int j = 0; j < 4; ++j) {
    int col = n0 + wn * 64 + j * 16 + ml;
    float bias = out_b[col];
#pragma unroll
    for (int i = 0; i < 8; ++i) {
      int trow = m0 + wm * 128 + i * 16 + q * 4;
#pragma unroll
      for (int v = 0; v < 4; ++v) {
        int t = trow + v;
        out[((size_t)(t & 3) * NN + (t >> 2)) * DD + col] = acc[i][j][v] + bias;
      }
    }
  }
}

extern "C" void kernel_launch(void* const* d_in, const int* in_sizes, int n_in,
                              void* d_out, int out_size, void* d_ws, size_t ws_size,
                              hipStream_t stream) {
  const float* x         = (const float*)d_in[0];
  const float* theta_log = (const float*)d_in[1];
  const float* gamma_log = (const float*)d_in[2];
  const float* nu_w      = (const float*)d_in[3];
  const float* nu_b      = (const float*)d_in[4];
  const float* in_w      = (const float*)d_in[5];
  const float* in_b      = (const float*)d_in[6];
  const float* out_w     = (const float*)d_in[7];
  const float* out_b     = (const float*)d_in[8];
  float* out = (float*)d_out;

  // Workspace layout: 148,897,792 B total (round 0 proved ws_size >= 216 MB)
  char* base = (char*)d_ws;
  unsigned short* U16 = (unsigned short*)base;                 //  67,108,864
  _Float16*       NU  = (_Float16*)(base + 67108864);          //  33,554,432
  unsigned short* Abf = (unsigned short*)(base + 100663296);   //  33,554,432
  unsigned short* W1  = (unsigned short*)(base + 134217728);   //   6,291,456
  unsigned short* W2  = (unsigned short*)(base + 140509184);   //   4,194,304
  float*          chunkA = (float*)(base + 144703488);         //   4,194,304

  conv_x_kernel<<<(BB * NN * DD) / 256, 256, 0, stream>>>(x, Abf);
  conv_w1_kernel<<<(3072 * 1024) / 256, 256, 0, stream>>>(in_w, nu_w, W1);
  conv_w2_kernel<<<(1024 * 1024) / 256, 256, 0, stream>>>(out_w, W2);
  gemm1_mfma<<<dim3(3072 / 256, TT / 256), 512, 0, stream>>>(
      Abf, W1, in_b, nu_b, gamma_log, U16, NU);
  scan_p1_kernel<<<(NC * BB * DD) / 256, 256, 0, stream>>>(U16, NU, theta_log, chunkA);
  scan_p2_kernel<<<(BB * DD) / 256, 256, 0, stream>>>(chunkA);
  scan_p3_kernel<<<NC * BB, 256, 0, stream>>>(U16, NU, theta_log, chunkA);
  gemm2_mfma<<<dim3(1024 / 256, TT / 256), 512, 0, stream>>>(U16, W2, out_b, out);
}

// Round 8
// 466.563 us; speedup vs baseline: 1.2447x; 1.2447x over previous
//
#include <hip/hip_runtime.h>
#include <math.h>
#include <stdint.h>

#define BB 4
#define NN 4096
#define DD 1024
#define TT (BB * NN)          // 16384 tokens
#define NC 64                 // scan chunks
#define CL (NN / NC)          // 64 steps per chunk

typedef __attribute__((ext_vector_type(8))) short bf16x8;
typedef __attribute__((ext_vector_type(4))) float f32x4;

// bf16 round-to-nearest-even (returns top-16 bit pattern)
__device__ inline unsigned short bf_rne(float v) {
  union { float f; uint32_t u; } x; x.f = v;
  uint32_t r = x.u + 0x7fffu + ((x.u >> 16) & 1u);
  return (unsigned short)(r >> 16);
}
__device__ inline float bf_to_f(unsigned short h) {
  union { float f; uint32_t u; } x; x.u = ((uint32_t)h) << 16;
  return x.f;
}

// async global->LDS, 16 bytes per lane, deposits at (wave-uniform base + lane*16)
__device__ inline void async16(const void* g, void* l) {
  __builtin_amdgcn_global_load_lds(
      (const __attribute__((address_space(1))) uint32_t*)g,
      (__attribute__((address_space(3))) uint32_t*)l, 16, 0, 0);
}

// ---------------------------------------------------------------------------
// conv_x: x (b,n,d) fp32 -> Abf (t = n*4+b, 1024) bf16.  float4-vectorized
// (G13): 16B loads / 8B stores per lane, 4x fewer instructions than scalar.
// ---------------------------------------------------------------------------
__global__ __launch_bounds__(256) void conv_x_kernel(
    const float* __restrict__ x, unsigned short* __restrict__ Abf) {
  int idx = blockIdx.x * 256 + threadIdx.x;     // over BB*NN*DD/4
  int k4 = idx & 255;                           // d/4
  int n = (idx >> 8) & 4095;
  int b = idx >> 20;
  float4 v = ((const float4*)x)[idx];
  ushort4 o = {bf_rne(v.x), bf_rne(v.y), bf_rne(v.z), bf_rne(v.w)};
  *(ushort4*)(Abf + (size_t)(n * 4 + b) * 1024 + k4 * 4) = o;
}

// ---------------------------------------------------------------------------
// conv_w (fused): W1 rows [in_w(2048); nu_w(1024)] bf16, and W2 (r,i)-
// interleaved from out_w. One launch instead of two.
// idx < 3M: W1 path; else W2 path (each W2 idx emits 2 shorts).
// ---------------------------------------------------------------------------
__global__ __launch_bounds__(256) void conv_w_kernel(
    const float* __restrict__ in_w, const float* __restrict__ nu_w,
    const float* __restrict__ out_w,
    unsigned short* __restrict__ W1, unsigned short* __restrict__ W2) {
  int idx = blockIdx.x * 256 + threadIdx.x;     // over 3072*1024 + 1024*1024
  if (idx < 3072 * 1024) {
    float v = (idx < 2048 * 1024) ? in_w[idx] : nu_w[idx - 2048 * 1024];
    W1[idx] = bf_rne(v);
  } else {
    int t = idx - 3072 * 1024;                  // over 1024*1024
    int j = t >> 10, d = t & 1023;
    W2[(size_t)j * 2048 + 2 * d]     = bf_rne(out_w[(size_t)j * 2048 + d]);
    W2[(size_t)j * 2048 + 2 * d + 1] = bf_rne(out_w[(size_t)j * 2048 + 1024 + d]);
  }
}

// ---------------------------------------------------------------------------
// GEMM1 (MFMA): z = Abf[t,:] . W1[e,:], K=1024 bf16.
// EXACT round-6 best kernel (491us total / 190us gemm1): 256x256 tile, BK=64,
// 8 waves (2Mx4N), 512 thr, LDS 128 KB, __launch_bounds__(512,2),
// counted-vmcnt dbuf + fine 4-phase interleave (T3+T4+T5) + T1 XCD swizzle.
// Verified: FETCH at 74MB partitioned floor, SQ_LDS_BANK_CONFLICT=0.
// r7 lesson: B-direct-to-VGPR regresses (exposed per-tile L2 latency) --
// A+B both staged via global_load_lds, one tile ahead, stays.
// Epilogue:
//   e < 2048 : U16[t,e]  = bf16( gamma[e>>1]*(z + in_b[e]) )   (u interleaved)
//   e >= 2048: NU[t,e']  = fp16( sigmoid(z + nu_b[e']) )
// ---------------------------------------------------------------------------
__global__ __launch_bounds__(512, 2) void gemm1_mfma(
    const unsigned short* __restrict__ A,
    const unsigned short* __restrict__ W1,
    const float* __restrict__ in_b, const float* __restrict__ nu_b,
    const float* __restrict__ gamma_log,
    unsigned short* __restrict__ U16, _Float16* __restrict__ NU) {
  __shared__ unsigned short As[2][16384];   // 2 x 32 KB
  __shared__ unsigned short Bs[2][16384];   // 2 x 32 KB
  const int tid = threadIdx.x;
  const int w = tid >> 6, l = tid & 63;
  const int q = l >> 4, ml = l & 15;
  // XCD-chunked swizzle (T1): orig%8 = XCD; each XCD owns an 8-m-tile band;
  // m fastest within band -> W1 panel reused 8x back-to-back in that L2.
  const int orig = blockIdx.x + gridDim.x * blockIdx.y;   // 0..767
  const int xcd = orig & 7;
  const int jj_ = orig >> 3;            // 0..95
  const int ntile = jj_ >> 3;           // 0..11
  const int mloc = jj_ & 7;             // 0..7
  const int m0 = (xcd * 8 + mloc) * 256;
  const int n0 = ntile * 256;
  const int wm = w & 1, wn = w >> 1;    // wm: row half, wn: col quarter

  f32x4 acc[8][4] = {};

  // part c stages k-slice kq=w for row-group c (A and B): 2 async16
  auto stage_part = [&](int p, int k0, int c) {
    async16(A  + (size_t)(m0 + c * 64 + l) * 1024 + k0 + w * 8,
            &As[p][(w * 256 + c * 64) * 8]);
    async16(W1 + (size_t)(n0 + c * 64 + l) * 1024 + k0 + w * 8,
            &Bs[p][(w * 256 + c * 64) * 8]);
  };

  // prologue: stage tile 0 fully (8 loads/wave in flight)
#pragma unroll
  for (int c = 0; c < 4; ++c) stage_part(0, 0, c);

  int cur = 0;
  for (int k0 = 0; k0 < 1024; k0 += 64) {
    const bool last = (k0 + 64 >= 1024);
    if (!last) {
      stage_part(cur ^ 1, k0 + 64, 0);                  // 8 -> 10 outstanding
      asm volatile("s_waitcnt vmcnt(2)" ::: "memory");  // tile t's 8 retired
    } else {
      asm volatile("s_waitcnt vmcnt(0)" ::: "memory");  // final drain
    }
    __builtin_amdgcn_s_barrier();        // buf[cur] staged (all waves)
    __builtin_amdgcn_sched_barrier(0);

    bf16x8 bfr[4], af[4];
#pragma unroll
    for (int ks = 0; ks < 2; ++ks) {
#pragma unroll
      for (int mh = 0; mh < 2; ++mh) {   // phase = ks*2 + mh
        if (mh == 0) {                   // bfr read once per ks, reused
#pragma unroll
          for (int j = 0; j < 4; ++j)
            bfr[j] = *(const bf16x8*)&Bs[cur][(((ks * 4 + q) * 256) + wn * 64 + j * 16 + ml) * 8];
        }
#pragma unroll
        for (int i = 0; i < 4; ++i)
          af[i] = *(const bf16x8*)&As[cur][(((ks * 4 + q) * 256) + wm * 128 + mh * 64 + i * 16 + ml) * 8];
        const int ph = ks * 2 + mh;
        if (!last && ph < 3) stage_part(cur ^ 1, k0 + 64, ph + 1);  // spread staging
        asm volatile("s_waitcnt lgkmcnt(0)" ::: "memory");
        __builtin_amdgcn_sched_barrier(0);   // rule #18: fence MFMA below the wait
        __builtin_amdgcn_s_setprio(1);
#pragma unroll
        for (int i = 0; i < 4; ++i)
#pragma unroll
          for (int j = 0; j < 4; ++j)
            acc[mh * 4 + i][j] = __builtin_amdgcn_mfma_f32_16x16x32_bf16(
                af[i], bfr[j], acc[mh * 4 + i][j], 0, 0, 0);
        __builtin_amdgcn_s_setprio(0);
        __builtin_amdgcn_sched_barrier(0);
        __builtin_amdgcn_s_barrier();        // phase end
      }
    }
    cur ^= 1;
  }

  if (n0 < 2048) {   // u columns (block-uniform)
#pragma unroll
    for (int j = 0; j < 4; ++j) {
      int col = n0 + wn * 64 + j * 16 + ml;
      float bias = in_b[col];
      float gam = expf(gamma_log[col >> 1]);
#pragma unroll
      for (int i = 0; i < 8; ++i) {
        int trow = m0 + wm * 128 + i * 16 + q * 4;
#pragma unroll
        for (int v = 0; v < 4; ++v)
          U16[(size_t)(trow + v) * 2048 + col] = bf_rne(gam * (acc[i][j][v] + bias));
      }
    }
  } else {           // nu columns
#pragma unroll
    for (int j = 0; j < 4; ++j) {
      int col = n0 + wn * 64 + j * 16 + ml;
      int c2 = col - 2048;
      float bias = nu_b[c2];
#pragma unroll
      for (int i = 0; i < 8; ++i) {
        int trow = m0 + wm * 128 + i * 16 + q * 4;
#pragma unroll
        for (int v = 0; v < 4; ++v) {
          float z = acc[i][j][v] + bias;
          NU[(size_t)(trow + v) * 1024 + c2] = (_Float16)(1.f / (1.f + expf(-z)));
        }
      }
    }
  }
}

// ---------------------------------------------------------------------------
// Scan phase 1: per (chunk c, batch b, channel dch) local scan from h=0.
// Emits (A_r, A_i, hend_r, hend_i), A = prod of lambda over the chunk.
// 1024 blocks = 4/CU, 16 waves/CU.
// ---------------------------------------------------------------------------
__global__ __launch_bounds__(256) void scan_p1_kernel(
    const unsigned short* __restrict__ U16, const _Float16* __restrict__ NU,
    const float* __restrict__ theta_log,
    float* __restrict__ chunkA) {
  int s = blockIdx.x * 256 + threadIdx.x;   // ((c*BB)+b)*DD + dch
  int dch = s & (DD - 1);
  int b = (s >> 10) & (BB - 1);
  int c = s >> 12;
  float theta = expf(theta_log[dch]);
  float ct = cosf(theta), st = sinf(theta);
  float hr = 0.f, hi = 0.f, Ar = 1.f, Ai = 0.f;
  for (int i = 0; i < CL; ++i) {
    int t = (c * CL + i) * 4 + b;
    ushort2 up = *(const ushort2*)(U16 + (size_t)t * 2048 + 2 * dch);
    float ur = bf_to_f(up.x), ui = bf_to_f(up.y);
    float nu = (float)NU[(size_t)t * 1024 + dch];
    float lr = nu * ct, li = nu * st;
    float hr2 = lr * hr - li * hi + ur;
    float hi2 = lr * hi + li * hr + ui;
    hr = hr2; hi = hi2;
    float Ar2 = lr * Ar - li * Ai;
    float Ai2 = lr * Ai + li * Ar;
    Ar = Ar2; Ai = Ai2;
  }
  float4 o = {Ar, Ai, hr, hi};
  *(float4*)(chunkA + (size_t)s * 4) = o;
}

// ---------------------------------------------------------------------------
// Scan phase 2: compose NC chunk summaries per channel; overwrite each
// entry's (z,w) slots in-place with that chunk's carry-in state.
// ---------------------------------------------------------------------------
__global__ __launch_bounds__(256) void scan_p2_kernel(
    float* __restrict__ chunkA) {
  int qx = blockIdx.x * 256 + threadIdx.x;   // b*DD + dch
  int dch = qx & (DD - 1);
  int b = qx >> 10;
  float cr = 0.f, ci = 0.f;
  for (int c = 0; c < NC; ++c) {
    size_t idx = ((size_t)(c * BB + b) * DD + dch) * 4;
    float4 v = *(const float4*)(chunkA + idx);
    float2 wv = {cr, ci};
    *(float2*)(chunkA + idx + 2) = wv;      // carry-in for chunk c
    float nr = v.x * cr - v.y * ci + v.z;
    float ni = v.x * ci + v.y * cr + v.w;
    cr = nr; ci = ni;
  }
}

// ---------------------------------------------------------------------------
// Scan phase 3 (round-8 change): 1 CHANNEL PER THREAD, 1024 blocks.
// Old: 256 blocks = 4 waves/CU for a serial latency-bound loop (the
// latency/occupancy regime). New: block = (c,b,quarter), thread owns one
// channel d = quarter*256+tid -> 4 blocks/CU, 16 waves/CU, 4x the TLP to
// hide the per-step load latency. Loads stay perfectly coalesced:
// ushort2 (256B/wave), half (128B/wave), write 256B/wave, in-place.
// ---------------------------------------------------------------------------
__global__ __launch_bounds__(256) void scan_p3_kernel(
    unsigned short* __restrict__ U16, const _Float16* __restrict__ NU,
    const float* __restrict__ theta_log, const float* __restrict__ chunkA) {
  const int quarter = blockIdx.x & 3;
  const int b = (blockIdx.x >> 2) & 3;
  const int c = blockIdx.x >> 4;
  const int d = quarter * 256 + threadIdx.x;
  float th = expf(theta_log[d]);
  float ct = cosf(th), st = sinf(th);
  const float* cp = chunkA + ((size_t)((c * 4 + b) * 1024) + d) * 4 + 2;
  float hr = cp[0], hi = cp[1];
  for (int i = 0; i < CL; ++i) {
    int t = (c * CL + i) * 4 + b;
    ushort2 uv = *(const ushort2*)(U16 + (size_t)t * 2048 + 2 * d);
    float nu = (float)NU[(size_t)t * 1024 + d];
    float lr = nu * ct, li = nu * st;
    float nhr = lr * hr - li * hi + bf_to_f(uv.x);
    float nhi = lr * hi + li * hr + bf_to_f(uv.y);
    hr = nhr; hi = nhi;
    ushort2 o = {bf_rne(nhr), bf_rne(nhi)};
    *(ushort2*)(U16 + (size_t)t * 2048 + 2 * d) = o;
  }
}

// ---------------------------------------------------------------------------
// GEMM2 (MFMA): out[t][j] = F[t,:] . W2[j,:] + out_b[j], K=2048 bf16, BK=64.
// F = U16 after scan_p3 (contiguous rows, stride 2048 shorts).
// EXACT round-6 best structure (fine 4-phase + T1, n-fastest per XCD band).
// ---------------------------------------------------------------------------
__global__ __launch_bounds__(512, 2) void gemm2_mfma(
    const unsigned short* __restrict__ F,
    const unsigned short* __restrict__ W2,
    const float* __restrict__ out_b,
    float* __restrict__ out) {
  __shared__ unsigned short As[2][16384];
  __shared__ unsigned short Bs[2][16384];
  const int tid = threadIdx.x;
  const int w = tid >> 6, l = tid & 63;
  const int q = l >> 4, ml = l & 15;
  const int orig = blockIdx.x + gridDim.x * blockIdx.y;   // 0..255
  const int xcd = orig & 7;
  const int jj_ = orig >> 3;            // 0..31
  const int mloc = jj_ >> 2;            // 0..7
  const int ntile = jj_ & 3;            // 0..3
  const int m0 = (xcd * 8 + mloc) * 256;
  const int n0 = ntile * 256;
  const int wm = w & 1, wn = w >> 1;

  f32x4 acc[8][4] = {};

  auto stage_part = [&](int p, int k0, int c) {
    async16(F  + (size_t)(m0 + c * 64 + l) * 2048 + k0 + w * 8,
            &As[p][(w * 256 + c * 64) * 8]);
    async16(W2 + (size_t)(n0 + c * 64 + l) * 2048 + k0 + w * 8,
            &Bs[p][(w * 256 + c * 64) * 8]);
  };

#pragma unroll
  for (int c = 0; c < 4; ++c) stage_part(0, 0, c);

  int cur = 0;
  for (int k0 = 0; k0 < 2048; k0 += 64) {
    const bool last = (k0 + 64 >= 2048);
    if (!last) {
      stage_part(cur ^ 1, k0 + 64, 0);
      asm volatile("s_waitcnt vmcnt(2)" ::: "memory");
    } else {
      asm volatile("s_waitcnt vmcnt(0)" ::: "memory");
    }
    __builtin_amdgcn_s_barrier();
    __builtin_amdgcn_sched_barrier(0);

    bf16x8 bfr[4], af[4];
#pragma unroll
    for (int ks = 0; ks < 2; ++ks) {
#pragma unroll
      for (int mh = 0; mh < 2; ++mh) {
        if (mh == 0) {
#pragma unroll
          for (int j = 0; j < 4; ++j)
            bfr[j] = *(const bf16x8*)&Bs[cur][(((ks * 4 + q) * 256) + wn * 64 + j * 16 + ml) * 8];
        }
#pragma unroll
        for (int i = 0; i < 4; ++i)
          af[i] = *(const bf16x8*)&As[cur][(((ks * 4 + q) * 256) + wm * 128 + mh * 64 + i * 16 + ml) * 8];
        const int ph = ks * 2 + mh;
        if (!last && ph < 3) stage_part(cur ^ 1, k0 + 64, ph + 1);
        asm volatile("s_waitcnt lgkmcnt(0)" ::: "memory");
        __builtin_amdgcn_sched_barrier(0);
        __builtin_amdgcn_s_setprio(1);
#pragma unroll
        for (int i = 0; i < 4; ++i)
#pragma unroll
          for (int j = 0; j < 4; ++j)
            acc[mh * 4 + i][j] = __builtin_amdgcn_mfma_f32_16x16x32_bf16(
                af[i], bfr[j], acc[mh * 4 + i][j], 0, 0, 0);
        __builtin_amdgcn_s_setprio(0);
        __builtin_amdgcn_sched_barrier(0);
        __builtin_amdgcn_s_barrier();
      }
    }
    cur ^= 1;
  }

#pragma unroll
  for (int j = 0; j < 4; ++j) {
    int col = n0 + wn * 64 + j * 16 + ml;
    float bias = out_b[col];
#pragma unroll
    for (int i = 0; i < 8; ++i) {
      int trow = m0 + wm * 128 + i * 16 + q * 4;
#pragma unroll
      for (int v = 0; v < 4; ++v) {
        int t = trow + v;
        out[((size_t)(t & 3) * NN + (t >> 2)) * DD + col] = acc[i][j][v] + bias;
      }
    }
  }
}

extern "C" void kernel_launch(void* const* d_in, const int* in_sizes, int n_in,
                              void* d_out, int out_size, void* d_ws, size_t ws_size,
                              hipStream_t stream) {
  const float* x         = (const float*)d_in[0];
  const float* theta_log = (const float*)d_in[1];
  const float* gamma_log = (const float*)d_in[2];
  const float* nu_w      = (const float*)d_in[3];
  const float* nu_b      = (const float*)d_in[4];
  const float* in_w      = (const float*)d_in[5];
  const float* in_b      = (const float*)d_in[6];
  const float* out_w     = (const float*)d_in[7];
  const float* out_b     = (const float*)d_in[8];
  float* out = (float*)d_out;

  // Workspace layout: 148,897,792 B total (round 0 proved ws_size >= 216 MB)
  char* base = (char*)d_ws;
  unsigned short* U16 = (unsigned short*)base;                 //  67,108,864
  _Float16*       NU  = (_Float16*)(base + 67108864);          //  33,554,432
  unsigned short* Abf = (unsigned short*)(base + 100663296);   //  33,554,432
  unsigned short* W1  = (unsigned short*)(base + 134217728);   //   6,291,456
  unsigned short* W2  = (unsigned short*)(base + 140509184);   //   4,194,304
  float*          chunkA = (float*)(base + 144703488);         //   4,194,304

  conv_x_kernel<<<(BB * NN * DD / 4) / 256, 256, 0, stream>>>(x, Abf);
  conv_w_kernel<<<(3072 * 1024 + 1024 * 1024) / 256, 256, 0, stream>>>(
      in_w, nu_w, out_w, W1, W2);
  gemm1_mfma<<<dim3(3072 / 256, TT / 256), 512, 0, stream>>>(
      Abf, W1, in_b, nu_b, gamma_log, U16, NU);
  scan_p1_kernel<<<(NC * BB * DD) / 256, 256, 0, stream>>>(U16, NU, theta_log, chunkA);
  scan_p2_kernel<<<(BB * DD) / 256, 256, 0, stream>>>(chunkA);
  scan_p3_kernel<<<NC * BB * 4, 256, 0, stream>>>(U16, NU, theta_log, chunkA);
  gemm2_mfma<<<dim3(1024 / 256, TT / 256), 512, 0, stream>>>(U16, W2, out_b, out);
}

// Round 9
// 445.573 us; speedup vs baseline: 1.3033x; 1.0471x over previous
//
#include <hip/hip_runtime.h>
#include <math.h>
#include <stdint.h>

#define BB 4
#define NN 4096
#define DD 1024
#define TT (BB * NN)          // 16384 tokens
#define NC 128                // scan chunks (r9: 64->128, halves serial chains)
#define CL (NN / NC)          // 32 steps per chunk

typedef __attribute__((ext_vector_type(8))) short bf16x8;
typedef __attribute__((ext_vector_type(4))) float f32x4;

// bf16 round-to-nearest-even (returns top-16 bit pattern)
__device__ inline unsigned short bf_rne(float v) {
  union { float f; uint32_t u; } x; x.f = v;
  uint32_t r = x.u + 0x7fffu + ((x.u >> 16) & 1u);
  return (unsigned short)(r >> 16);
}
__device__ inline float bf_to_f(unsigned short h) {
  union { float f; uint32_t u; } x; x.u = ((uint32_t)h) << 16;
  return x.f;
}

// async global->LDS, 16 bytes per lane, deposits at (wave-uniform base + lane*16)
__device__ inline void async16(const void* g, void* l) {
  __builtin_amdgcn_global_load_lds(
      (const __attribute__((address_space(1))) uint32_t*)g,
      (__attribute__((address_space(3))) uint32_t*)l, 16, 0, 0);
}

// ---------------------------------------------------------------------------
// conv_x: x (b,n,d) fp32 -> Abf (t = n*4+b, 1024) bf16.  float4-vectorized
// (G13): 16B loads / 8B stores per lane.
// ---------------------------------------------------------------------------
__global__ __launch_bounds__(256) void conv_x_kernel(
    const float* __restrict__ x, unsigned short* __restrict__ Abf) {
  int idx = blockIdx.x * 256 + threadIdx.x;     // over BB*NN*DD/4
  int k4 = idx & 255;                           // d/4
  int n = (idx >> 8) & 4095;
  int b = idx >> 20;
  float4 v = ((const float4*)x)[idx];
  ushort4 o = {bf_rne(v.x), bf_rne(v.y), bf_rne(v.z), bf_rne(v.w)};
  *(ushort4*)(Abf + (size_t)(n * 4 + b) * 1024 + k4 * 4) = o;
}

// ---------------------------------------------------------------------------
// conv_w (fused): W1 rows [in_w(2048); nu_w(1024)] bf16, and W2 (r,i)-
// interleaved from out_w. One launch instead of two.
// ---------------------------------------------------------------------------
__global__ __launch_bounds__(256) void conv_w_kernel(
    const float* __restrict__ in_w, const float* __restrict__ nu_w,
    const float* __restrict__ out_w,
    unsigned short* __restrict__ W1, unsigned short* __restrict__ W2) {
  int idx = blockIdx.x * 256 + threadIdx.x;     // over 3072*1024 + 1024*1024
  if (idx < 3072 * 1024) {
    float v = (idx < 2048 * 1024) ? in_w[idx] : nu_w[idx - 2048 * 1024];
    W1[idx] = bf_rne(v);
  } else {
    int t = idx - 3072 * 1024;                  // over 1024*1024
    int j = t >> 10, d = t & 1023;
    W2[(size_t)j * 2048 + 2 * d]     = bf_rne(out_w[(size_t)j * 2048 + d]);
    W2[(size_t)j * 2048 + 2 * d + 1] = bf_rne(out_w[(size_t)j * 2048 + 1024 + d]);
  }
}

// ---------------------------------------------------------------------------
// GEMM1 (MFMA): z = Abf[t,:] . W1[e,:], K=1024 bf16.
// K-loop: EXACT r6/r8 verified structure (190us): 256x256 tile, BK=64,
// 8 waves (2Mx4N), 512 thr, LDS 128 KB, __launch_bounds__(512,2),
// counted-vmcnt dbuf + fine 4-phase interleave (T3+T4+T5) + T1 XCD swizzle.
// FETCH at 74MB partitioned floor, SQ_LDS_BANK_CONFLICT=0. DO NOT TOUCH.
// r9 change: EPILOGUE LOOP ORDER ONLY -- j innermost so the 4 stores that
// fill each 128B line (cols j*16+ml, j=0..3) issue back-to-back. r8 measured
// WRITE_SIZE 208MB vs 96 ideal = 2.2x amplification from 32B partial-line
// stores separated by 32 row-hopping iterations.
// Epilogue:
//   e < 2048 : U16[t,e]  = bf16( gamma[e>>1]*(z + in_b[e]) )   (u interleaved)
//   e >= 2048: NU[t,e']  = fp16( sigmoid(z + nu_b[e']) )
// ---------------------------------------------------------------------------
__global__ __launch_bounds__(512, 2) void gemm1_mfma(
    const unsigned short* __restrict__ A,
    const unsigned short* __restrict__ W1,
    const float* __restrict__ in_b, const float* __restrict__ nu_b,
    const float* __restrict__ gamma_log,
    unsigned short* __restrict__ U16, _Float16* __restrict__ NU) {
  __shared__ unsigned short As[2][16384];   // 2 x 32 KB
  __shared__ unsigned short Bs[2][16384];   // 2 x 32 KB
  const int tid = threadIdx.x;
  const int w = tid >> 6, l = tid & 63;
  const int q = l >> 4, ml = l & 15;
  // XCD-chunked swizzle (T1): orig%8 = XCD; each XCD owns an 8-m-tile band;
  // m fastest within band -> W1 panel reused 8x back-to-back in that L2.
  const int orig = blockIdx.x + gridDim.x * blockIdx.y;   // 0..767
  const int xcd = orig & 7;
  const int jj_ = orig >> 3;            // 0..95
  const int ntile = jj_ >> 3;           // 0..11
  const int mloc = jj_ & 7;             // 0..7
  const int m0 = (xcd * 8 + mloc) * 256;
  const int n0 = ntile * 256;
  const int wm = w & 1, wn = w >> 1;    // wm: row half, wn: col quarter

  f32x4 acc[8][4] = {};

  // part c stages k-slice kq=w for row-group c (A and B): 2 async16
  auto stage_part = [&](int p, int k0, int c) {
    async16(A  + (size_t)(m0 + c * 64 + l) * 1024 + k0 + w * 8,
            &As[p][(w * 256 + c * 64) * 8]);
    async16(W1 + (size_t)(n0 + c * 64 + l) * 1024 + k0 + w * 8,
            &Bs[p][(w * 256 + c * 64) * 8]);
  };

  // prologue: stage tile 0 fully (8 loads/wave in flight)
#pragma unroll
  for (int c = 0; c < 4; ++c) stage_part(0, 0, c);

  int cur = 0;
  for (int k0 = 0; k0 < 1024; k0 += 64) {
    const bool last = (k0 + 64 >= 1024);
    if (!last) {
      stage_part(cur ^ 1, k0 + 64, 0);                  // 8 -> 10 outstanding
      asm volatile("s_waitcnt vmcnt(2)" ::: "memory");  // tile t's 8 retired
    } else {
      asm volatile("s_waitcnt vmcnt(0)" ::: "memory");  // final drain
    }
    __builtin_amdgcn_s_barrier();        // buf[cur] staged (all waves)
    __builtin_amdgcn_sched_barrier(0);

    bf16x8 bfr[4], af[4];
#pragma unroll
    for (int ks = 0; ks < 2; ++ks) {
#pragma unroll
      for (int mh = 0; mh < 2; ++mh) {   // phase = ks*2 + mh
        if (mh == 0) {                   // bfr read once per ks, reused
#pragma unroll
          for (int j = 0; j < 4; ++j)
            bfr[j] = *(const bf16x8*)&Bs[cur][(((ks * 4 + q) * 256) + wn * 64 + j * 16 + ml) * 8];
        }
#pragma unroll
        for (int i = 0; i < 4; ++i)
          af[i] = *(const bf16x8*)&As[cur][(((ks * 4 + q) * 256) + wm * 128 + mh * 64 + i * 16 + ml) * 8];
        const int ph = ks * 2 + mh;
        if (!last && ph < 3) stage_part(cur ^ 1, k0 + 64, ph + 1);  // spread staging
        asm volatile("s_waitcnt lgkmcnt(0)" ::: "memory");
        __builtin_amdgcn_sched_barrier(0);   // rule #18: fence MFMA below the wait
        __builtin_amdgcn_s_setprio(1);
#pragma unroll
        for (int i = 0; i < 4; ++i)
#pragma unroll
          for (int j = 0; j < 4; ++j)
            acc[mh * 4 + i][j] = __builtin_amdgcn_mfma_f32_16x16x32_bf16(
                af[i], bfr[j], acc[mh * 4 + i][j], 0, 0, 0);
        __builtin_amdgcn_s_setprio(0);
        __builtin_amdgcn_sched_barrier(0);
        __builtin_amdgcn_s_barrier();        // phase end
      }
    }
    cur ^= 1;
  }

  if (n0 < 2048) {   // u columns (block-uniform)
    float bias[4], gam[4];
#pragma unroll
    for (int j = 0; j < 4; ++j) {
      int col = n0 + wn * 64 + j * 16 + ml;
      bias[j] = in_b[col];
      gam[j] = expf(gamma_log[col >> 1]);
    }
#pragma unroll
    for (int i = 0; i < 8; ++i) {
      int trow = m0 + wm * 128 + i * 16 + q * 4;
#pragma unroll
      for (int v = 0; v < 4; ++v) {
        size_t rowb = (size_t)(trow + v) * 2048;
#pragma unroll
        for (int j = 0; j < 4; ++j) {   // j innermost: 4x32B -> one 128B line
          int col = n0 + wn * 64 + j * 16 + ml;
          U16[rowb + col] = bf_rne(gam[j] * (acc[i][j][v] + bias[j]));
        }
      }
    }
  } else {           // nu columns
    float bias[4];
#pragma unroll
    for (int j = 0; j < 4; ++j)
      bias[j] = nu_b[n0 + wn * 64 + j * 16 + ml - 2048];
#pragma unroll
    for (int i = 0; i < 8; ++i) {
      int trow = m0 + wm * 128 + i * 16 + q * 4;
#pragma unroll
      for (int v = 0; v < 4; ++v) {
        size_t rowb = (size_t)(trow + v) * 1024;
#pragma unroll
        for (int j = 0; j < 4; ++j) {
          int c2 = n0 + wn * 64 + j * 16 + ml - 2048;
          float z = acc[i][j][v] + bias[j];
          NU[rowb + c2] = (_Float16)(1.f / (1.f + expf(-z)));
        }
      }
    }
  }
}

// ---------------------------------------------------------------------------
// Scan phase 1: per (chunk c, batch b, channel dch) local scan from h=0.
// Emits (A_r, A_i, hend_r, hend_i), A = prod of lambda over the chunk.
// NC=128 -> 2048 blocks = 8/CU, serial chain 32 steps.
// ---------------------------------------------------------------------------
__global__ __launch_bounds__(256) void scan_p1_kernel(
    const unsigned short* __restrict__ U16, const _Float16* __restrict__ NU,
    const float* __restrict__ theta_log,
    float* __restrict__ chunkA) {
  int s = blockIdx.x * 256 + threadIdx.x;   // ((c*BB)+b)*DD + dch
  int dch = s & (DD - 1);
  int b = (s >> 10) & (BB - 1);
  int c = s >> 12;
  float theta = expf(theta_log[dch]);
  float ct = cosf(theta), st = sinf(theta);
  float hr = 0.f, hi = 0.f, Ar = 1.f, Ai = 0.f;
  for (int i = 0; i < CL; ++i) {
    int t = (c * CL + i) * 4 + b;
    ushort2 up = *(const ushort2*)(U16 + (size_t)t * 2048 + 2 * dch);
    float ur = bf_to_f(up.x), ui = bf_to_f(up.y);
    float nu = (float)NU[(size_t)t * 1024 + dch];
    float lr = nu * ct, li = nu * st;
    float hr2 = lr * hr - li * hi + ur;
    float hi2 = lr * hi + li * hr + ui;
    hr = hr2; hi = hi2;
    float Ar2 = lr * Ar - li * Ai;
    float Ai2 = lr * Ai + li * Ar;
    Ar = Ar2; Ai = Ai2;
  }
  float4 o = {Ar, Ai, hr, hi};
  *(float4*)(chunkA + (size_t)s * 4) = o;
}

// ---------------------------------------------------------------------------
// Scan phase 2: compose NC chunk summaries per channel; overwrite each
// entry's (z,w) slots in-place with that chunk's carry-in state.
// ---------------------------------------------------------------------------
__global__ __launch_bounds__(256) void scan_p2_kernel(
    float* __restrict__ chunkA) {
  int qx = blockIdx.x * 256 + threadIdx.x;   // b*DD + dch
  int dch = qx & (DD - 1);
  int b = qx >> 10;
  float cr = 0.f, ci = 0.f;
  for (int c = 0; c < NC; ++c) {
    size_t idx = ((size_t)(c * BB + b) * DD + dch) * 4;
    float4 v = *(const float4*)(chunkA + idx);
    float2 wv = {cr, ci};
    *(float2*)(chunkA + idx + 2) = wv;      // carry-in for chunk c
    float nr = v.x * cr - v.y * ci + v.z;
    float ni = v.x * ci + v.y * cr + v.w;
    cr = nr; ci = ni;
  }
}

// ---------------------------------------------------------------------------
// Scan phase 3: 1 channel/thread, block = (c,b,quarter). NC=128 -> 2048
// blocks = 8/CU, 32-step serial chain (halved vs r8). Loads coalesced:
// ushort2 256B/wave, half 128B/wave; in-place bf16 feature write.
// ---------------------------------------------------------------------------
__global__ __launch_bounds__(256) void scan_p3_kernel(
    unsigned short* __restrict__ U16, const _Float16* __restrict__ NU,
    const float* __restrict__ theta_log, const float* __restrict__ chunkA) {
  const int quarter = blockIdx.x & 3;
  const int b = (blockIdx.x >> 2) & 3;
  const int c = blockIdx.x >> 4;
  const int d = quarter * 256 + threadIdx.x;
  float th = expf(theta_log[d]);
  float ct = cosf(th), st = sinf(th);
  const float* cp = chunkA + ((size_t)((c * 4 + b) * 1024) + d) * 4 + 2;
  float hr = cp[0], hi = cp[1];
  for (int i = 0; i < CL; ++i) {
    int t = (c * CL + i) * 4 + b;
    ushort2 uv = *(const ushort2*)(U16 + (size_t)t * 2048 + 2 * d);
    float nu = (float)NU[(size_t)t * 1024 + d];
    float lr = nu * ct, li = nu * st;
    float nhr = lr * hr - li * hi + bf_to_f(uv.x);
    float nhi = lr * hi + li * hr + bf_to_f(uv.y);
    hr = nhr; hi = nhi;
    ushort2 o = {bf_rne(nhr), bf_rne(nhi)};
    *(ushort2*)(U16 + (size_t)t * 2048 + 2 * d) = o;
  }
}

// ---------------------------------------------------------------------------
// GEMM2 (MFMA): out[t][j] = F[t,:] . W2[j,:] + out_b[j], K=2048 bf16, BK=64.
// K-loop: EXACT r6/r8 verified structure. r9: epilogue j-innermost
// (4x64B = 256B consecutive fp32 stores per row).
// ---------------------------------------------------------------------------
__global__ __launch_bounds__(512, 2) void gemm2_mfma(
    const unsigned short* __restrict__ F,
    const unsigned short* __restrict__ W2,
    const float* __restrict__ out_b,
    float* __restrict__ out) {
  __shared__ unsigned short As[2][16384];
  __shared__ unsigned short Bs[2][16384];
  const int tid = threadIdx.x;
  const int w = tid >> 6, l = tid & 63;
  const int q = l >> 4, ml = l & 15;
  const int orig = blockIdx.x + gridDim.x * blockIdx.y;   // 0..255
  const int xcd = orig & 7;
  const int jj_ = orig >> 3;            // 0..31
  const int mloc = jj_ >> 2;            // 0..7
  const int ntile = jj_ & 3;            // 0..3
  const int m0 = (xcd * 8 + mloc) * 256;
  const int n0 = ntile * 256;
  const int wm = w & 1, wn = w >> 1;

  f32x4 acc[8][4] = {};

  auto stage_part = [&](int p, int k0, int c) {
    async16(F  + (size_t)(m0 + c * 64 + l) * 2048 + k0 + w * 8,
            &As[p][(w * 256 + c * 64) * 8]);
    async16(W2 + (size_t)(n0 + c * 64 + l) * 2048 + k0 + w * 8,
            &Bs[p][(w * 256 + c * 64) * 8]);
  };

#pragma unroll
  for (int c = 0; c < 4; ++c) stage_part(0, 0, c);

  int cur = 0;
  for (int k0 = 0; k0 < 2048; k0 += 64) {
    const bool last = (k0 + 64 >= 2048);
    if (!last) {
      stage_part(cur ^ 1, k0 + 64, 0);
      asm volatile("s_waitcnt vmcnt(2)" ::: "memory");
    } else {
      asm volatile("s_waitcnt vmcnt(0)" ::: "memory");
    }
    __builtin_amdgcn_s_barrier();
    __builtin_amdgcn_sched_barrier(0);

    bf16x8 bfr[4], af[4];
#pragma unroll
    for (int ks = 0; ks < 2; ++ks) {
#pragma unroll
      for (int mh = 0; mh < 2; ++mh) {
        if (mh == 0) {
#pragma unroll
          for (int j = 0; j < 4; ++j)
            bfr[j] = *(const bf16x8*)&Bs[cur][(((ks * 4 + q) * 256) + wn * 64 + j * 16 + ml) * 8];
        }
#pragma unroll
        for (int i = 0; i < 4; ++i)
          af[i] = *(const bf16x8*)&As[cur][(((ks * 4 + q) * 256) + wm * 128 + mh * 64 + i * 16 + ml) * 8];
        const int ph = ks * 2 + mh;
        if (!last && ph < 3) stage_part(cur ^ 1, k0 + 64, ph + 1);
        asm volatile("s_waitcnt lgkmcnt(0)" ::: "memory");
        __builtin_amdgcn_sched_barrier(0);
        __builtin_amdgcn_s_setprio(1);
#pragma unroll
        for (int i = 0; i < 4; ++i)
#pragma unroll
          for (int j = 0; j < 4; ++j)
            acc[mh * 4 + i][j] = __builtin_amdgcn_mfma_f32_16x16x32_bf16(
                af[i], bfr[j], acc[mh * 4 + i][j], 0, 0, 0);
        __builtin_amdgcn_s_setprio(0);
        __builtin_amdgcn_sched_barrier(0);
        __builtin_amdgcn_s_barrier();
      }
    }
    cur ^= 1;
  }

  float bias[4];
#pragma unroll
  for (int j = 0; j < 4; ++j)
    bias[j] = out_b[n0 + wn * 64 + j * 16 + ml];
#pragma unroll
  for (int i = 0; i < 8; ++i) {
    int trow = m0 + wm * 128 + i * 16 + q * 4;
#pragma unroll
    for (int v = 0; v < 4; ++v) {
      int t = trow + v;
      size_t ob = ((size_t)(t & 3) * NN + (t >> 2)) * DD;
#pragma unroll
      for (int j = 0; j < 4; ++j) {   // j innermost: 4x64B consecutive
        int col = n0 + wn * 64 + j * 16 + ml;
        out[ob + col] = acc[i][j][v] + bias[j];
      }
    }
  }
}

extern "C" void kernel_launch(void* const* d_in, const int* in_sizes, int n_in,
                              void* d_out, int out_size, void* d_ws, size_t ws_size,
                              hipStream_t stream) {
  const float* x         = (const float*)d_in[0];
  const float* theta_log = (const float*)d_in[1];
  const float* gamma_log = (const float*)d_in[2];
  const float* nu_w      = (const float*)d_in[3];
  const float* nu_b      = (const float*)d_in[4];
  const float* in_w      = (const float*)d_in[5];
  const float* in_b      = (const float*)d_in[6];
  const float* out_w     = (const float*)d_in[7];
  const float* out_b     = (const float*)d_in[8];
  float* out = (float*)d_out;

  // Workspace layout: ~153 MB total (ws_size >= 216 MB proven earlier)
  char* base = (char*)d_ws;
  unsigned short* U16 = (unsigned short*)base;                 //  67,108,864
  _Float16*       NU  = (_Float16*)(base + 67108864);          //  33,554,432
  unsigned short* Abf = (unsigned short*)(base + 100663296);   //  33,554,432
  unsigned short* W1  = (unsigned short*)(base + 134217728);   //   6,291,456
  unsigned short* W2  = (unsigned short*)(base + 140509184);   //   4,194,304
  float*          chunkA = (float*)(base + 144703488);         //   8,388,608 (NC=128)

  conv_x_kernel<<<(BB * NN * DD / 4) / 256, 256, 0, stream>>>(x, Abf);
  conv_w_kernel<<<(3072 * 1024 + 1024 * 1024) / 256, 256, 0, stream>>>(
      in_w, nu_w, out_w, W1, W2);
  gemm1_mfma<<<dim3(3072 / 256, TT / 256), 512, 0, stream>>>(
      Abf, W1, in_b, nu_b, gamma_log, U16, NU);
  scan_p1_kernel<<<(NC * BB * DD) / 256, 256, 0, stream>>>(U16, NU, theta_log, chunkA);
  scan_p2_kernel<<<(BB * DD) / 256, 256, 0, stream>>>(chunkA);
  scan_p3_kernel<<<NC * BB * 4, 256, 0, stream>>>(U16, NU, theta_log, chunkA);
  gemm2_mfma<<<dim3(1024 / 256, TT / 256), 512, 0, stream>>>(U16, W2, out_b, out);
}